// Round 2
// baseline (375.032 us; speedup 1.0000x reference)
//
#include <hip/hip_runtime.h>

typedef unsigned short USH;
typedef unsigned int   UIN;

static constexpr int Bn = 1024;    // batch
static constexpr int Hn = 200;     // history length
static constexpr int Dn = 128;     // embed/hidden
static constexpr int Dh = 64;      // half embed
static constexpr int NITEM = 50000;
static constexpr int NREG  = 1000;
static constexpr int AB_A_BLOCKS = NITEM / 16;        // 3125
static constexpr int AB_B_BLOCKS = (NREG + 15) / 16;  // 63

__device__ __forceinline__ float2 tb2f2(UIN p) {  // bf16 pair (ws tables) -> 2 floats
  float2 r;
  r.x = __uint_as_float(p << 16);
  r.y = __uint_as_float(p & 0xffff0000u);
  return r;
}
__device__ __forceinline__ USH f2b(float f) {  // fp32 -> bf16 rne
  UIN x = __float_as_uint(f);
  return (USH)((x + 0x7fffu + ((x >> 16) & 1u)) >> 16);
}

// ---------------------------------------------------------------------------
// g[c] = sum_i row[tr[i]] * row[hr[i,c]],  row = embed_dist[uid]  (fp32)
// ---------------------------------------------------------------------------
__global__ __launch_bounds__(256) void g_kernel(
    const int* __restrict__ hregion, const int* __restrict__ tregion,
    const float* __restrict__ embed_dist, const int* __restrict__ uid,
    float* __restrict__ g) {
  int c = threadIdx.x;
  const float* row = embed_dist + (size_t)uid[0] * NREG;  // 4KB, L1-resident
  float acc = 0.f;
  int ibase = blockIdx.x * 16;
  for (int ii = 0; ii < 16; ii++) {
    int i = ibase + ii;
    float td = row[tregion[i]];               // wave-uniform broadcast
    if (c < Hn) acc += td * row[hregion[(size_t)i * Hn + c]];
  }
  if (c < Hn) atomicAdd(&g[c], acc);
}

// ---------------------------------------------------------------------------
// A[item][j] = dot(Et[item][0:64], Wk[j][0:64])   -> bf16 table
// B[reg][j]  = dot(Er[reg][0:64],  Wk[j][64:128]) -> bf16 table
// Thread: fixed j (tid&127), 8 items; Wk half-row (64 fp32) in VGPRs.
// ---------------------------------------------------------------------------
__global__ __launch_bounds__(256) void ab_kernel(
    const float* __restrict__ Et, const float* __restrict__ Er,
    const float* __restrict__ Wk, USH* __restrict__ A, USH* __restrict__ Bt) {
  int blk = blockIdx.x, tid = threadIdx.x;
  const float* E; USH* Out; int nmax, base, koff;
  if (blk < AB_A_BLOCKS) { E = Et; Out = A;  nmax = NITEM; base = blk * 16; koff = 0; }
  else { E = Er; Out = Bt; nmax = NREG; base = (blk - AB_A_BLOCKS) * 16; koff = 64; }
  int j = tid & 127, grp = tid >> 7;  // grp wave-uniform

  float wkf[64];
  {
    const float4* wp = reinterpret_cast<const float4*>(Wk + (size_t)j * Dn + koff);
#pragma unroll
    for (int q4 = 0; q4 < 16; q4++) {
      float4 w = wp[q4];
      wkf[q4 * 4 + 0] = w.x; wkf[q4 * 4 + 1] = w.y;
      wkf[q4 * 4 + 2] = w.z; wkf[q4 * 4 + 3] = w.w;
    }
  }
#pragma unroll
  for (int ii = 0; ii < 8; ii++) {
    int item = base + grp * 8 + ii;
    if (item < nmax) {
      const float4* ep = reinterpret_cast<const float4*>(E + (size_t)item * Dh);
      float acc = 0.f;
#pragma unroll
      for (int q4 = 0; q4 < 16; q4++) {
        float4 e = ep[q4];
        acc += e.x * wkf[q4 * 4 + 0] + e.y * wkf[q4 * 4 + 1]
             + e.z * wkf[q4 * 4 + 2] + e.w * wkf[q4 * 4 + 3];
      }
      Out[(size_t)item * Dn + j] = f2b(acc);
    }
  }
}

// ---------------------------------------------------------------------------
// One block per batch row i.
// ---------------------------------------------------------------------------
__global__ __launch_bounds__(256) void main_kernel(
    const int* __restrict__ history, const int* __restrict__ target,
    const int* __restrict__ hregion, const int* __restrict__ tregion,
    const float* __restrict__ hv, const float* __restrict__ dist_mat,
    const float* __restrict__ Et, const float* __restrict__ Er,
    const float* __restrict__ Wq, const float* __restrict__ Wv,
    const float* __restrict__ g, const USH* __restrict__ A,
    const USH* __restrict__ Bt, float* __restrict__ out) {
  __shared__ float tgtE[128], qv[128], uv[128];
  __shared__ float scores[Hn], s1[Hn], s2[Hn];
  __shared__ float red[8];
  int i = blockIdx.x, tid = threadIdx.x, lane = tid & 63, wave = tid >> 6;
  int tgt_i = target[i], tr_i = tregion[i];

  if (tid < Hn) scores[tid] = 0.f;
  if (tid < 64)       tgtE[tid] = Et[(size_t)tgt_i * Dh + tid];
  else if (tid < 128) tgtE[tid] = Er[(size_t)tr_i * Dh + (tid - 64)];
  __syncthreads();

  // q[j] = (1/sqrt(128)) * dot(Wq[j,:], tgtE)   (waves 0-1)
  // u[d] = sum_j tgtE[j] * Wv[j][d]             (waves 2-3)
  if (tid < 128) {
    int j = tid; float acc = 0.f;
    const float4* wp = reinterpret_cast<const float4*>(Wq + (size_t)j * Dn);
#pragma unroll
    for (int q4 = 0; q4 < 32; q4++) {
      float4 w = wp[q4];
      const float* tv = &tgtE[q4 * 4];
      acc += w.x * tv[0] + w.y * tv[1] + w.z * tv[2] + w.w * tv[3];
    }
    qv[j] = acc * 0.088388347648318447f;  // 1/sqrt(128) folded into q
  } else {
    int d = tid - 128; float acc = 0.f;
    for (int j = 0; j < 128; j++) acc += Wv[(size_t)j * Dn + d] * tgtE[j];
    uv[d] = acc;
  }
  __syncthreads();

  const int* hrow = history + (size_t)i * Hn;
  const int* rrow = hregion + (size_t)i * Hn;

  // Per wave: one t at a time. k[t][j] = A[item][j]+B[reg][j]; element m=128t+j
  // feeds scores[m%200] with weight q[m/200] (faithful reshape semantics).
  for (int t = wave; t < Hn; t += 4) {
    int item = hrow[t], reg = rrow[t];  // wave-uniform
    UIN av = *reinterpret_cast<const UIN*>(A  + (size_t)item * Dn + 2 * lane);
    UIN bv = *reinterpret_cast<const UIN*>(Bt + (size_t)reg  * Dn + 2 * lane);
    float2 af = tb2f2(av), bf = tb2f2(bv);
    int m0 = t * Dn + 2 * lane;
    {
      UIN a0 = (UIN)m0 / 200u; int c0 = m0 - (int)a0 * 200;
      atomicAdd(&scores[c0], qv[a0] * (af.x + bf.x));
    }
    {
      int m1 = m0 + 1;
      UIN a1 = (UIN)m1 / 200u; int c1 = m1 - (int)a1 * 200;
      atomicAdd(&scores[c1], qv[a1] * (af.y + bf.y));
    }
    // s1[t] = dot(hist_emb, u), s2[t] = dot(hist_emb, tgt_emb)
    float et = Et[(size_t)item * Dh + lane];
    float er = Er[(size_t)reg  * Dh + lane];
    float p1 = et * uv[lane] + er * uv[64 + lane];
    float p2 = et * tgtE[lane] + er * tgtE[64 + lane];
    for (int off = 32; off > 0; off >>= 1) {
      p1 += __shfl_down(p1, off, 64);
      p2 += __shfl_down(p2, off, 64);
    }
    if (lane == 0) { s1[t] = p1; s2[t] = p2; }
  }
  __syncthreads();

  // epilogue: masked exp, beta-normalized attention, geo, final dot + sigmoid
  float ea = 0.f;
  if (tid < Hn) ea = (hrow[tid] != tgt_i) ? __expf(scores[tid]) : 0.f;
  float wsum = ea;
  for (int off = 32; off > 0; off >>= 1) wsum += __shfl_down(wsum, off, 64);
  if (lane == 0) red[wave] = wsum;
  __syncthreads();
  float esum = red[0] + red[1] + red[2] + red[3];
  float inv = esum > 0.f ? 1.f / sqrtf(esum) : 0.f;  // exp_sum ** 0.5 (BETA)
  float part = 0.f;
  if (tid < Hn) {
    float attn = ea * inv;
    float gc = g[tid]; gc = gc > 0.f ? gc : 0.f;  // relu
    float dm = dist_mat[(size_t)i * Hn + tid];
    float geo = __expf(-dm / (gc + 1.f));
    part = (attn + geo) * s1[tid] + hv[tid] * s2[tid];
  }
  __syncthreads();  // protect red[] reuse
  for (int off = 32; off > 0; off >>= 1) part += __shfl_down(part, off, 64);
  if (lane == 0) red[wave] = part;
  __syncthreads();
  if (tid == 0) {
    float pred = red[0] + red[1] + red[2] + red[3];
    out[i] = 1.f / (1.f + __expf(-pred));
  }
}

extern "C" void kernel_launch(void* const* d_in, const int* in_sizes, int n_in,
                              void* d_out, int out_size, void* d_ws, size_t ws_size,
                              hipStream_t stream) {
  const int*   history = (const int*)d_in[0];
  const int*   target  = (const int*)d_in[1];
  const int*   hregion = (const int*)d_in[2];
  const int*   tregion = (const int*)d_in[3];
  const float* hv      = (const float*)d_in[4];
  const float* dist    = (const float*)d_in[5];
  const int*   uid     = (const int*)d_in[6];
  const float* Et      = (const float*)d_in[7];
  const float* Er      = (const float*)d_in[8];
  const float* Edist   = (const float*)d_in[9];
  const float* Wq      = (const float*)d_in[10];
  const float* Wk      = (const float*)d_in[11];
  const float* Wv      = (const float*)d_in[12];

  float* g = (float*)d_ws;                          // 200 f32 (1KB slot)
  USH* A   = (USH*)((char*)d_ws + 1024);            // 50000*128 bf16 = 12.8MB
  USH* Bt  = A + (size_t)NITEM * Dn;                // 1000*128 bf16 = 256KB
  float* out = (float*)d_out;

  hipMemsetAsync(g, 0, Hn * sizeof(float), stream);
  g_kernel<<<Bn / 16, 256, 0, stream>>>(hregion, tregion, Edist, uid, g);
  ab_kernel<<<AB_A_BLOCKS + AB_B_BLOCKS, 256, 0, stream>>>(Et, Er, Wk, A, Bt);
  main_kernel<<<Bn, 256, 0, stream>>>(history, target, hregion, tregion, hv, dist,
                                      Et, Er, Wq, Wv, g, A, Bt, out);
}

// Round 3
// 227.691 us; speedup vs baseline: 1.6471x; 1.6471x over previous
//
#include <hip/hip_runtime.h>

typedef unsigned short USH;
typedef unsigned int   UIN;

static constexpr int Bn = 1024;    // batch
static constexpr int Hn = 200;     // history length
static constexpr int Dn = 128;     // embed/hidden
static constexpr int Dh = 64;      // half embed
static constexpr int NITEM = 50000;
static constexpr int NREG  = 1000;
static constexpr int AB_A_BLOCKS = (NITEM + 63) / 64;  // 782
static constexpr int AB_B_BLOCKS = (NREG  + 63) / 64;  // 16

__device__ __forceinline__ float bf2f(USH u) {
  return __uint_as_float(((UIN)u) << 16);
}
__device__ __forceinline__ USH f2b(float f) {  // fp32 -> bf16 rne
  UIN x = __float_as_uint(f);
  return (USH)((x + 0x7fffu + ((x >> 16) & 1u)) >> 16);
}

// ---------------------------------------------------------------------------
// g[c] = sum_i row[tr[i]] * row[hr[i,c]],  row = embed_dist[uid]  (fp32)
// ---------------------------------------------------------------------------
__global__ __launch_bounds__(256) void g_kernel(
    const int* __restrict__ hregion, const int* __restrict__ tregion,
    const float* __restrict__ embed_dist, const int* __restrict__ uid,
    float* __restrict__ g) {
  int c = threadIdx.x;
  const float* row = embed_dist + (size_t)uid[0] * NREG;  // 4KB, L1-resident
  float acc = 0.f;
  int ibase = blockIdx.x * 16;
  for (int ii = 0; ii < 16; ii++) {
    int i = ibase + ii;
    float td = row[tregion[i]];               // wave-uniform broadcast
    if (c < Hn) acc += td * row[hregion[(size_t)i * Hn + c]];
  }
  if (c < Hn) atomicAdd(&g[c], acc);
}

// ---------------------------------------------------------------------------
// A[item][j] = dot(Et[item][0:64], Wk[j][0:64])   -> bf16 table
// B[reg][j]  = dot(Er[reg][0:64],  Wk[j][64:128]) -> bf16 table
// v2: Wk half staged TRANSPOSED in LDS (wt[k][j], stride 129: conflict-free
// reads, coalesced global loads). 64 items/block; E-row loads wave-uniform
// (scalarized). VALU-bound.
// ---------------------------------------------------------------------------
__global__ __launch_bounds__(256) void ab_kernel(
    const float* __restrict__ Et, const float* __restrict__ Er,
    const float* __restrict__ Wk, USH* __restrict__ A, USH* __restrict__ Bt) {
  __shared__ float wt[64 * 129];  // 33KB
  int blk = blockIdx.x, tid = threadIdx.x;
  const float* E; USH* Out; int nmax, base, koff;
  if (blk < AB_A_BLOCKS) { E = Et; Out = A;  nmax = NITEM; base = blk * 64; koff = 0; }
  else { E = Er; Out = Bt; nmax = NREG; base = (blk - AB_A_BLOCKS) * 64; koff = 64; }

  // stage: wt[k*129 + j] = Wk[j][koff + k]  (2048 float4 reads, coalesced)
#pragma unroll
  for (int p = 0; p < 8; p++) {
    int idx = p * 256 + tid;     // 0..2047
    int row = idx >> 4;          // j: 0..127
    int c4  = idx & 15;          // k-quad: 0..15
    float4 w = *reinterpret_cast<const float4*>(Wk + (size_t)row * Dn + koff + c4 * 4);
    wt[(c4 * 4 + 0) * 129 + row] = w.x;
    wt[(c4 * 4 + 1) * 129 + row] = w.y;
    wt[(c4 * 4 + 2) * 129 + row] = w.z;
    wt[(c4 * 4 + 3) * 129 + row] = w.w;
  }
  __syncthreads();

  int j = tid & 127, g = tid >> 7;  // g wave-uniform
  float wkf[64];
#pragma unroll
  for (int k = 0; k < 64; k++) wkf[k] = wt[k * 129 + j];

  for (int ii = 0; ii < 32; ii++) {
    int item = base + g * 32 + ii;
    if (item < nmax) {
      const float4* ep = reinterpret_cast<const float4*>(E + (size_t)item * Dh);
      float acc = 0.f;
#pragma unroll
      for (int k4 = 0; k4 < 16; k4++) {
        float4 e = ep[k4];
        acc += e.x * wkf[k4 * 4 + 0] + e.y * wkf[k4 * 4 + 1]
             + e.z * wkf[k4 * 4 + 2] + e.w * wkf[k4 * 4 + 3];
      }
      Out[(size_t)item * Dn + j] = f2b(acc);
    }
  }
}

// ---------------------------------------------------------------------------
// One block per batch row i. v3: thread-per-c scores (m = a*200+c -> t=m>>7,
// j=m&127), thread-per-t s1/s2. No LDS atomics, no per-t shuffle chains,
// 128 independent gathers per thread (unrolled -> deep MLP).
// ---------------------------------------------------------------------------
__global__ __launch_bounds__(256) void main_kernel(
    const int* __restrict__ history, const int* __restrict__ target,
    const int* __restrict__ hregion, const int* __restrict__ tregion,
    const float* __restrict__ hv, const float* __restrict__ dist_mat,
    const float* __restrict__ Et, const float* __restrict__ Er,
    const float* __restrict__ Wq, const float* __restrict__ Wv,
    const float* __restrict__ g, const USH* __restrict__ A,
    const USH* __restrict__ Bt, float* __restrict__ out) {
  __shared__ float tgtE[128], qv[128], uv[128];
  __shared__ int li[Hn], lr[Hn];
  __shared__ float red[8];
  int i = blockIdx.x, tid = threadIdx.x, lane = tid & 63, wave = tid >> 6;
  int tgt_i = target[i], tr_i = tregion[i];
  const int* hrow = history + (size_t)i * Hn;
  const int* rrow = hregion + (size_t)i * Hn;

  if (tid < Hn) { li[tid] = hrow[tid]; lr[tid] = rrow[tid]; }
  if (tid < 64)       tgtE[tid] = Et[(size_t)tgt_i * Dh + tid];
  else if (tid < 128) tgtE[tid] = Er[(size_t)tr_i * Dh + (tid - 64)];
  __syncthreads();

  // phase 1: q[j] (waves 0-1, per-thread Wq row), u[d] (waves 2-3, coalesced
  // column sweep). Both short chains, once per block.
  if (tid < 128) {
    int j = tid; float acc = 0.f;
    const float4* wp = reinterpret_cast<const float4*>(Wq + (size_t)j * Dn);
#pragma unroll
    for (int q4 = 0; q4 < 32; q4++) {
      float4 w = wp[q4];
      const float* tv = &tgtE[q4 * 4];
      acc += w.x * tv[0] + w.y * tv[1] + w.z * tv[2] + w.w * tv[3];
    }
    qv[j] = acc * 0.088388347648318447f;  // 1/sqrt(128) folded into q
  } else {
    int d = tid - 128; float acc = 0.f;
#pragma unroll 8
    for (int j = 0; j < 128; j++) acc += Wv[(size_t)j * Dn + d] * tgtE[j];
    uv[d] = acc;
  }
  __syncthreads();

  float ea = 0.f, sc1 = 0.f, sc2 = 0.f;
  if (tid < Hn) {
    // scores[c]: 128 independent bf16-table gathers
    int c = tid;
    float acc = 0.f;
#pragma unroll 8
    for (int a = 0; a < 128; a++) {
      int m = a * 200 + c;
      int t = m >> 7, j = m & 127;
      float kv = bf2f(A[(size_t)li[t] * Dn + j]) + bf2f(Bt[(size_t)lr[t] * Dn + j]);
      acc += qv[a] * kv;  // qv[a] uniform -> LDS broadcast
    }
    // s1/s2: per-thread dot over own history row
    int t = tid;
    const float4* ep = reinterpret_cast<const float4*>(Et + (size_t)li[t] * Dh);
    const float4* rp = reinterpret_cast<const float4*>(Er + (size_t)lr[t] * Dh);
    float p1 = 0.f, p2 = 0.f;
#pragma unroll
    for (int k4 = 0; k4 < 16; k4++) {
      float4 e = ep[k4], r = rp[k4];
      const float* u0 = &uv[k4 * 4];        const float* t0 = &tgtE[k4 * 4];
      const float* u1 = &uv[64 + k4 * 4];   const float* t1 = &tgtE[64 + k4 * 4];
      p1 += e.x * u0[0] + e.y * u0[1] + e.z * u0[2] + e.w * u0[3]
          + r.x * u1[0] + r.y * u1[1] + r.z * u1[2] + r.w * u1[3];
      p2 += e.x * t0[0] + e.y * t0[1] + e.z * t0[2] + e.w * t0[3]
          + r.x * t1[0] + r.y * t1[1] + r.z * t1[2] + r.w * t1[3];
    }
    sc1 = p1; sc2 = p2;
    ea = (li[tid] != tgt_i) ? __expf(acc) : 0.f;  // masked exp(score)
  }

  // exp-sum reduction (the only cross-thread communication)
  float wsum = ea;
  for (int off = 32; off > 0; off >>= 1) wsum += __shfl_down(wsum, off, 64);
  if (lane == 0) red[wave] = wsum;
  __syncthreads();
  float esum = red[0] + red[1] + red[2] + red[3];
  float inv = esum > 0.f ? 1.f / sqrtf(esum) : 0.f;  // exp_sum ** 0.5 (BETA)

  float part = 0.f;
  if (tid < Hn) {
    float attn = ea * inv;
    float gc = g[tid]; gc = gc > 0.f ? gc : 0.f;  // relu
    float dm = dist_mat[(size_t)i * Hn + tid];
    float geo = __expf(-dm / (gc + 1.f));
    part = (attn + geo) * sc1 + hv[tid] * sc2;
  }
  __syncthreads();  // protect red[] reuse
  for (int off = 32; off > 0; off >>= 1) part += __shfl_down(part, off, 64);
  if (lane == 0) red[wave] = part;
  __syncthreads();
  if (tid == 0) {
    float pred = red[0] + red[1] + red[2] + red[3];
    out[i] = 1.f / (1.f + __expf(-pred));
  }
}

extern "C" void kernel_launch(void* const* d_in, const int* in_sizes, int n_in,
                              void* d_out, int out_size, void* d_ws, size_t ws_size,
                              hipStream_t stream) {
  const int*   history = (const int*)d_in[0];
  const int*   target  = (const int*)d_in[1];
  const int*   hregion = (const int*)d_in[2];
  const int*   tregion = (const int*)d_in[3];
  const float* hv      = (const float*)d_in[4];
  const float* dist    = (const float*)d_in[5];
  const int*   uid     = (const int*)d_in[6];
  const float* Et      = (const float*)d_in[7];
  const float* Er      = (const float*)d_in[8];
  const float* Edist   = (const float*)d_in[9];
  const float* Wq      = (const float*)d_in[10];
  const float* Wk      = (const float*)d_in[11];
  const float* Wv      = (const float*)d_in[12];

  float* g = (float*)d_ws;                          // 200 f32 (1KB slot)
  USH* A   = (USH*)((char*)d_ws + 1024);            // 50000*128 bf16 = 12.8MB
  USH* Bt  = A + (size_t)NITEM * Dn;                // 1000*128 bf16 = 256KB
  float* out = (float*)d_out;

  hipMemsetAsync(g, 0, Hn * sizeof(float), stream);
  g_kernel<<<Bn / 16, 256, 0, stream>>>(hregion, tregion, Edist, uid, g);
  ab_kernel<<<AB_A_BLOCKS + AB_B_BLOCKS, 256, 0, stream>>>(Et, Er, Wk, A, Bt);
  main_kernel<<<Bn, 256, 0, stream>>>(history, target, hregion, tregion, hv, dist,
                                      Et, Er, Wq, Wv, g, A, Bt, out);
}